// Round 2
// 2956.843 us; speedup vs baseline: 1.0513x; 1.0513x over previous
//
#include <hip/hip_runtime.h>
#include <hip/hip_bf16.h>
#include <hip/hip_fp16.h>

// Problem dims (fixed by the reference).
#define B_ 256
#define T_ 2048
#define D_ 128

typedef __attribute__((ext_vector_type(8))) short bf16x8;   // MFMA A/B frag (8 bf16)
typedef __attribute__((ext_vector_type(4))) float f32x4;    // MFMA C/D frag
typedef __attribute__((ext_vector_type(4))) unsigned int u32x4;

__device__ __forceinline__ unsigned int bf_rne(float f) {
    unsigned int u = __builtin_bit_cast(unsigned int, f);
    return (u + 0x7FFFu + ((u >> 16) & 1u)) >> 16;
}
__device__ __forceinline__ unsigned int pack_bf2(float lo, float hi) {
    return bf_rne(lo) | (bf_rne(hi) << 16);
}
__device__ __forceinline__ float bits_as_f(unsigned int u) {
    return __builtin_bit_cast(float, u);
}
__device__ __forceinline__ unsigned int pack_h2(float lo, float hi) {
    unsigned int a = (unsigned int)__half_as_ushort(__float2half_rn(lo));
    unsigned int b = (unsigned int)__half_as_ushort(__float2half_rn(hi));
    return a | (b << 16);
}
__device__ __forceinline__ float h_lo(unsigned int g) {
    return __half2float(__ushort_as_half((unsigned short)(g & 0xFFFFu)));
}
__device__ __forceinline__ float h_hi(unsigned int g) {
    return __half2float(__ushort_as_half((unsigned short)(g >> 16)));
}
__device__ __forceinline__ float sigmoid_f(float x) {
    return __builtin_amdgcn_rcpf(1.0f + __expf(-x));
}
__device__ __forceinline__ float tanh_f(float x) {
    return 1.0f - 2.0f * __builtin_amdgcn_rcpf(__expf(2.0f * x) + 1.0f);
}
// Two f32 -> packed bf16 pair (RNE). Union pun (not bit_cast: __hip_bfloat162
// is not trivially copyable on this ROCm).
__device__ __forceinline__ unsigned int cvt_pk_bf16(float a, float b) {
    union { __hip_bfloat162 h; unsigned int u; } r;
    r.h = __float22bfloat162_rn(make_float2(a, b));
    return r.u;
}

// Load an A-fragment of a row-major [D][D] fp32 weight matrix as bf16.
// A-layout (16x16x32): lane holds A[m = lane&15][k = (lane>>4)*8 + j], j=0..7.
__device__ __forceinline__ bf16x8 load_w_frag(const float* __restrict__ W, int row, int dbase) {
    const float4 a = *(const float4*)(W + row * D_ + dbase);
    const float4 b = *(const float4*)(W + row * D_ + dbase + 4);
    union { bf16x8 v; unsigned int u[4]; } r;
    r.u[0] = pack_bf2(a.x, a.y);
    r.u[1] = pack_bf2(a.z, a.w);
    r.u[2] = pack_bf2(b.x, b.y);
    r.u[3] = pack_bf2(b.z, b.w);
    return r.v;
}

// ---------------------------------------------------------------------------
// Phase 1: P = ev@We^T + be + bp (fp32 -> d_out, consumed then overwritten by
//          the chain), gates = sigmoid(ev@{Wl,Ww}^T + {bl,bw}) packed fp16
//          {leak, write} -> d_ws. 512 thr = 8 waves, wave w owns e-slice 16w.
// ---------------------------------------------------------------------------
__global__ __launch_bounds__(512, 4) void proj_kernel(
    const float* __restrict__ ev,
    const float* __restrict__ We, const float* __restrict__ be,
    const float* __restrict__ Wl, const float* __restrict__ bl,
    const float* __restrict__ Ww, const float* __restrict__ bw,
    const float* __restrict__ bp,
    float* __restrict__ P, unsigned int* __restrict__ G)
{
    __shared__ __align__(16) unsigned short evs[16 * 136];

    const int tid  = threadIdx.x;
    const int wave = tid >> 6, lane = tid & 63;
    const int l15  = lane & 15, quad = lane >> 4;
    const int ebase = wave << 4;
    const int ecol  = ebase + (quad << 2);

    bf16x8 aWe[4], aWl[4], aWw[4];
#pragma unroll
    for (int k = 0; k < 4; ++k) {
        const int dbase = k * 32 + quad * 8;
        aWe[k] = load_w_frag(We, ebase + l15, dbase);
        aWl[k] = load_w_frag(Wl, ebase + l15, dbase);
        aWw[k] = load_w_frag(Ww, ebase + l15, dbase);
    }
    float biasP[4], biasL[4], biasW[4];
#pragma unroll
    for (int r = 0; r < 4; ++r) {
        const int e = ecol + r;
        biasP[r] = be[e] + bp[e];
        biasL[r] = bl[e];
        biasW[r] = bw[e];
    }

    const int srow = tid >> 5;
    const int sd   = (tid & 31) << 2;
    const int NT   = (B_ * T_) / 16;

    int tile = blockIdx.x;
    float4 stg = {0.f, 0.f, 0.f, 0.f};
    if (tile < NT)
        stg = *(const float4*)(ev + (size_t)(tile * 16 + srow) * D_ + sd);

    for (; tile < NT; tile += gridDim.x) {
        *(uint2*)&evs[srow * 136 + sd] =
            make_uint2(pack_bf2(stg.x, stg.y), pack_bf2(stg.z, stg.w));
        __syncthreads();
        const int nt = tile + gridDim.x;
        if (nt < NT)
            stg = *(const float4*)(ev + (size_t)(nt * 16 + srow) * D_ + sd);

        f32x4 accP = {biasP[0], biasP[1], biasP[2], biasP[3]};
        f32x4 accL = {biasL[0], biasL[1], biasL[2], biasL[3]};
        f32x4 accW = {biasW[0], biasW[1], biasW[2], biasW[3]};
#pragma unroll
        for (int k = 0; k < 4; ++k) {
            const bf16x8 bfrag = *(const bf16x8*)&evs[l15 * 136 + k * 32 + quad * 8];
            accP = __builtin_amdgcn_mfma_f32_16x16x32_bf16(aWe[k], bfrag, accP, 0, 0, 0);
            accL = __builtin_amdgcn_mfma_f32_16x16x32_bf16(aWl[k], bfrag, accL, 0, 0, 0);
            accW = __builtin_amdgcn_mfma_f32_16x16x32_bf16(aWw[k], bfrag, accW, 0, 0, 0);
        }
        __syncthreads();

        const size_t row_g = (size_t)tile * 16 + l15;
        *(f32x4*)(P + row_g * D_ + ecol) = accP;
        u32x4 gv;
#pragma unroll
        for (int r = 0; r < 4; ++r)
            gv[r] = pack_h2(sigmoid_f(accL[r]), sigmoid_f(accW[r]));
        *(u32x4*)(G + row_g * D_ + ecol) = gv;
    }
}

// ---------------------------------------------------------------------------
// Phase 2: recurrence. 16 blocks x 512 thr (8 waves, 2/SIMD); each block owns
// 16 batch rows; wave w owns features [16w, 16w+16) as ONE 16-wide MFMA acc
// group with Wp A-frags in registers. Halving per-wave work vs the 4-wave
// version shortens the serial VALU tail, and 2 waves/SIMD overlap their
// dependent-latency chains. The 8-deep MFMA chain is split into 4 parallel
// depth-2 chains (one per k-tile, hi then lo) + 3 f32x4 adds. hi/lo bf16
// split via packed bf16 convert instead of manual bit-twiddling.
// Barrier = raw `s_waitcnt lgkmcnt(0); s_barrier` (LDS visibility only) so the
// t+2 global prefetches and the belief store stay in flight across steps.
// ---------------------------------------------------------------------------
__device__ __forceinline__ void chain_step(
    const bf16x8 (&aW)[4],
    bf16x8 (&fhi)[4], bf16x8 (&flo)[4],
    f32x4& Pr, u32x4& Gr,
    f32x4& bold,
    const float* __restrict__ p0,
    const unsigned int* __restrict__ g0,
    float* __restrict__ o0,
    unsigned short* bhi, unsigned short* blo,   // LDS buffer written this step
    int t, int lw0, int lr, int quad)
{
    // 4 parallel accumulator chains, depth 2 (hi then lo per k-tile).
    f32x4 a0 = Pr;
    f32x4 a1 = {0.f, 0.f, 0.f, 0.f};
    f32x4 a2 = {0.f, 0.f, 0.f, 0.f};
    f32x4 a3 = {0.f, 0.f, 0.f, 0.f};
    const u32x4 g = Gr;
    if (t + 2 < T_) {
        Pr = *(const f32x4*)(p0 + (size_t)(t + 2) * D_);
        Gr = *(const u32x4*)(g0 + (size_t)(t + 2) * D_);
    }
    a0 = __builtin_amdgcn_mfma_f32_16x16x32_bf16(aW[0], fhi[0], a0, 0, 0, 0);
    a1 = __builtin_amdgcn_mfma_f32_16x16x32_bf16(aW[1], fhi[1], a1, 0, 0, 0);
    a2 = __builtin_amdgcn_mfma_f32_16x16x32_bf16(aW[2], fhi[2], a2, 0, 0, 0);
    a3 = __builtin_amdgcn_mfma_f32_16x16x32_bf16(aW[3], fhi[3], a3, 0, 0, 0);
    a0 = __builtin_amdgcn_mfma_f32_16x16x32_bf16(aW[0], flo[0], a0, 0, 0, 0);
    a1 = __builtin_amdgcn_mfma_f32_16x16x32_bf16(aW[1], flo[1], a1, 0, 0, 0);
    a2 = __builtin_amdgcn_mfma_f32_16x16x32_bf16(aW[2], flo[2], a2, 0, 0, 0);
    a3 = __builtin_amdgcn_mfma_f32_16x16x32_bf16(aW[3], flo[3], a3, 0, 0, 0);
    const f32x4 acc = (a0 + a1) + (a2 + a3);

    f32x4 bn;
#pragma unroll
    for (int r = 0; r < 4; ++r) {
        const float th = tanh_f(acc[r]);
        bn[r] = h_lo(g[r]) * bold[r] + h_hi(g[r]) * th;
    }
    bold = bn;
    *(f32x4*)(o0 + (size_t)t * D_) = bn;

    // hi/lo bf16 split: hi = rne_bf16(v), lo = rne_bf16(v - hi). One packed
    // convert per pair + shl/and extraction + sub.
    const unsigned int h0 = cvt_pk_bf16(bn[0], bn[1]);
    const unsigned int h1 = cvt_pk_bf16(bn[2], bn[3]);
    const float f0 = bits_as_f(h0 << 16);
    const float f1 = bits_as_f(h0 & 0xFFFF0000u);
    const float f2 = bits_as_f(h1 << 16);
    const float f3 = bits_as_f(h1 & 0xFFFF0000u);
    const unsigned int l0 = cvt_pk_bf16(bn[0] - f0, bn[1] - f1);
    const unsigned int l1 = cvt_pk_bf16(bn[2] - f2, bn[3] - f3);
    *(uint2*)&bhi[lw0] = make_uint2(h0, h1);
    *(uint2*)&blo[lw0] = make_uint2(l0, l1);

    // LDS-only barrier: do NOT drain vmcnt (prefetches/stores stay in flight).
    asm volatile("s_waitcnt lgkmcnt(0)\n\ts_barrier" ::: "memory");

#pragma unroll
    for (int k = 0; k < 4; ++k) {
        fhi[k] = *(const bf16x8*)&bhi[lr + k * 32 + quad * 8];
        flo[k] = *(const bf16x8*)&blo[lr + k * 32 + quad * 8];
    }
}

__global__ __launch_bounds__(512) void chain_kernel(
    const float* __restrict__ Wp,
    const unsigned int* __restrict__ G,
    float* __restrict__ Out)
{
    __shared__ __align__(16) unsigned short bl_hi[2][16 * 136];
    __shared__ __align__(16) unsigned short bl_lo[2][16 * 136];

    const int tid  = threadIdx.x;
    const int wave = tid >> 6, lane = tid & 63;   // wave in [0,8)
    const int l15  = lane & 15, quad = lane >> 4;
    const int e0   = (wave << 4) + (quad << 2);   // this wave's 16-feature slice
    const int b    = (blockIdx.x << 4) + l15;     // batch row

    bf16x8 aW[4];
#pragma unroll
    for (int k = 0; k < 4; ++k)
        aW[k] = load_w_frag(Wp, (wave << 4) + l15, k * 32 + quad * 8);

    const size_t srow = (size_t)b * T_ * D_;
    const float*        __restrict__ p0 = Out + srow + e0;
    const unsigned int* __restrict__ g0 = G   + srow + e0;
    float*              __restrict__ o0 = Out + srow + e0;

    // 2-deep prefetch in NAMED registers (no dynamically-indexed arrays!).
    f32x4 Pa = *(const f32x4*)(p0);
    u32x4 Ga = *(const u32x4*)(g0);
    f32x4 Pb = *(const f32x4*)(p0 + D_);
    u32x4 Gb = *(const u32x4*)(g0 + D_);

    bf16x8 fhi[4], flo[4];
#pragma unroll
    for (int k = 0; k < 4; ++k) { fhi[k] = (bf16x8)0; flo[k] = (bf16x8)0; }
    f32x4 bold = {0.f, 0.f, 0.f, 0.f};

    const int lw0 = l15 * 136 + e0;
    const int lr  = l15 * 136;

    for (int t = 0; t < T_; t += 2) {
        // even step writes/reads buffer 1, odd step buffer 0
        chain_step(aW, fhi, flo, Pa, Ga, bold, p0, g0, o0,
                   &bl_hi[1][0], &bl_lo[1][0], t, lw0, lr, quad);
        chain_step(aW, fhi, flo, Pb, Gb, bold, p0, g0, o0,
                   &bl_hi[0][0], &bl_lo[0][0], t + 1, lw0, lr, quad);
    }
}

extern "C" void kernel_launch(void* const* d_in, const int* in_sizes, int n_in,
                              void* d_out, int out_size, void* d_ws, size_t ws_size,
                              hipStream_t stream)
{
    const float* ev = (const float*)d_in[0];
    const float* We = (const float*)d_in[1];
    const float* be = (const float*)d_in[2];
    const float* Wp = (const float*)d_in[3];
    const float* bp = (const float*)d_in[4];
    const float* Wl = (const float*)d_in[5];
    const float* bl = (const float*)d_in[6];
    const float* Ww = (const float*)d_in[7];
    const float* bw = (const float*)d_in[8];
    float* out = (float*)d_out;
    unsigned int* G = (unsigned int*)d_ws; // B*T*D*4 = 256 MiB of workspace
    (void)in_sizes; (void)n_in; (void)out_size; (void)ws_size;

    proj_kernel<<<2048, 512, 0, stream>>>(ev, We, be, Wl, bl, Ww, bw, bp, out, G);
    chain_kernel<<<16, 512, 0, stream>>>(Wp, G, out);
}

// Round 4
// 2558.353 us; speedup vs baseline: 1.2151x; 1.1558x over previous
//
#include <hip/hip_runtime.h>
#include <hip/hip_bf16.h>
#include <hip/hip_fp16.h>

// Problem dims (fixed by the reference).
#define B_ 256
#define T_ 2048
#define D_ 128

typedef __attribute__((ext_vector_type(8))) short bf16x8;   // MFMA A/B frag (8 bf16)
typedef __attribute__((ext_vector_type(4))) float f32x4;    // MFMA C/D frag
typedef __attribute__((ext_vector_type(4))) unsigned int u32x4;

__device__ __forceinline__ unsigned int bf_rne(float f) {
    unsigned int u = __builtin_bit_cast(unsigned int, f);
    return (u + 0x7FFFu + ((u >> 16) & 1u)) >> 16;
}
__device__ __forceinline__ unsigned int pack_bf2(float lo, float hi) {
    return bf_rne(lo) | (bf_rne(hi) << 16);
}
__device__ __forceinline__ float bits_as_f(unsigned int u) {
    return __builtin_bit_cast(float, u);
}
__device__ __forceinline__ unsigned int pack_h2(float lo, float hi) {
    unsigned int a = (unsigned int)__half_as_ushort(__float2half_rn(lo));
    unsigned int b = (unsigned int)__half_as_ushort(__float2half_rn(hi));
    return a | (b << 16);
}
__device__ __forceinline__ float h_lo(unsigned int g) {
    return __half2float(__ushort_as_half((unsigned short)(g & 0xFFFFu)));
}
__device__ __forceinline__ float h_hi(unsigned int g) {
    return __half2float(__ushort_as_half((unsigned short)(g >> 16)));
}
__device__ __forceinline__ float sigmoid_f(float x) {
    return __builtin_amdgcn_rcpf(1.0f + __expf(-x));
}
__device__ __forceinline__ float tanh_f(float x) {
    return 1.0f - 2.0f * __builtin_amdgcn_rcpf(__expf(2.0f * x) + 1.0f);
}
// Two f32 -> packed bf16 pair (RNE). Union pun (not bit_cast: __hip_bfloat162
// is not trivially copyable on this ROCm).
__device__ __forceinline__ unsigned int cvt_pk_bf16(float a, float b) {
    union { __hip_bfloat162 h; unsigned int u; } r;
    r.h = __float22bfloat162_rn(make_float2(a, b));
    return r.u;
}

// Load an A-fragment of a row-major [D][D] fp32 weight matrix as bf16.
// A-layout (16x16x32): lane holds A[m = lane&15][k = (lane>>4)*8 + j], j=0..7.
__device__ __forceinline__ bf16x8 load_w_frag(const float* W, int row, int dbase) {
    const float4 a = *(const float4*)(W + row * D_ + dbase);
    const float4 b = *(const float4*)(W + row * D_ + dbase + 4);
    union { bf16x8 v; unsigned int u[4]; } r;
    r.u[0] = pack_bf2(a.x, a.y);
    r.u[1] = pack_bf2(a.z, a.w);
    r.u[2] = pack_bf2(b.x, b.y);
    r.u[3] = pack_bf2(b.z, b.w);
    return r.v;
}

// ---------------------------------------------------------------------------
// Phase 1: P = ev@We^T + be + bp (fp32 -> Pbuf), gates = sigmoid(ev@{Wl,Ww}^T
//          + {bl,bw}) packed fp16 {leak, write} -> G. 512 thr = 8 waves,
//          wave w owns e-slice 16w.
// ---------------------------------------------------------------------------
__global__ __launch_bounds__(512, 4) void proj_kernel(
    const float* __restrict__ ev,
    const float* __restrict__ We, const float* __restrict__ be,
    const float* __restrict__ Wl, const float* __restrict__ bl,
    const float* __restrict__ Ww, const float* __restrict__ bw,
    const float* __restrict__ bp,
    float* __restrict__ P, unsigned int* __restrict__ G)
{
    __shared__ __align__(16) unsigned short evs[16 * 136];

    const int tid  = threadIdx.x;
    const int wave = tid >> 6, lane = tid & 63;
    const int l15  = lane & 15, quad = lane >> 4;
    const int ebase = wave << 4;
    const int ecol  = ebase + (quad << 2);

    bf16x8 aWe[4], aWl[4], aWw[4];
#pragma unroll
    for (int k = 0; k < 4; ++k) {
        const int dbase = k * 32 + quad * 8;
        aWe[k] = load_w_frag(We, ebase + l15, dbase);
        aWl[k] = load_w_frag(Wl, ebase + l15, dbase);
        aWw[k] = load_w_frag(Ww, ebase + l15, dbase);
    }
    float biasP[4], biasL[4], biasW[4];
#pragma unroll
    for (int r = 0; r < 4; ++r) {
        const int e = ecol + r;
        biasP[r] = be[e] + bp[e];
        biasL[r] = bl[e];
        biasW[r] = bw[e];
    }

    const int srow = tid >> 5;
    const int sd   = (tid & 31) << 2;
    const int NT   = (B_ * T_) / 16;

    int tile = blockIdx.x;
    float4 stg = {0.f, 0.f, 0.f, 0.f};
    if (tile < NT)
        stg = *(const float4*)(ev + (size_t)(tile * 16 + srow) * D_ + sd);

    for (; tile < NT; tile += gridDim.x) {
        *(uint2*)&evs[srow * 136 + sd] =
            make_uint2(pack_bf2(stg.x, stg.y), pack_bf2(stg.z, stg.w));
        __syncthreads();
        const int nt = tile + gridDim.x;
        if (nt < NT)
            stg = *(const float4*)(ev + (size_t)(nt * 16 + srow) * D_ + sd);

        f32x4 accP = {biasP[0], biasP[1], biasP[2], biasP[3]};
        f32x4 accL = {biasL[0], biasL[1], biasL[2], biasL[3]};
        f32x4 accW = {biasW[0], biasW[1], biasW[2], biasW[3]};
#pragma unroll
        for (int k = 0; k < 4; ++k) {
            const bf16x8 bfrag = *(const bf16x8*)&evs[l15 * 136 + k * 32 + quad * 8];
            accP = __builtin_amdgcn_mfma_f32_16x16x32_bf16(aWe[k], bfrag, accP, 0, 0, 0);
            accL = __builtin_amdgcn_mfma_f32_16x16x32_bf16(aWl[k], bfrag, accL, 0, 0, 0);
            accW = __builtin_amdgcn_mfma_f32_16x16x32_bf16(aWw[k], bfrag, accW, 0, 0, 0);
        }
        __syncthreads();

        const size_t row_g = (size_t)tile * 16 + l15;
        *(f32x4*)(P + row_g * D_ + ecol) = accP;
        u32x4 gv;
#pragma unroll
        for (int r = 0; r < 4; ++r)
            gv[r] = pack_h2(sigmoid_f(accL[r]), sigmoid_f(accW[r]));
        *(u32x4*)(G + row_g * D_ + ecol) = gv;
    }
}

// ---------------------------------------------------------------------------
// Phase 2: recurrence. 16 blocks x 512 thr (8 waves, 2/SIMD); each block owns
// 16 batch rows; wave w owns features [16w, 16w+16). Two instantiations:
//   chain_split: P in its own workspace region, pointers __restrict__ -> the
//     compiler can prove the t+2 prefetch never aliases the belief store and
//     keeps it in flight with a counted vmcnt before the use (no per-step
//     drain of ~900cy HBM latency on the serial path).
//   chain_alias: exact R2 behavior (P aliased onto Out) as a fallback when
//     ws_size can't hold P+G.
// Barrier = raw `s_waitcnt lgkmcnt(0); s_barrier` (LDS visibility only).
// ---------------------------------------------------------------------------
__device__ __forceinline__ void chain_step(
    const bf16x8 (&aW)[4],
    bf16x8 (&fhi)[4], bf16x8 (&flo)[4],
    f32x4& Pr, u32x4& Gr,
    f32x4& bold,
    const float* p0,
    const unsigned int* g0,
    float* o0,
    unsigned short* bhi, unsigned short* blo,   // LDS buffer written this step
    int t, int lw0, int lr, int quad)
{
    // 4 parallel accumulator chains, depth 2 (hi then lo per k-tile).
    f32x4 a0 = Pr;
    f32x4 a1 = {0.f, 0.f, 0.f, 0.f};
    f32x4 a2 = {0.f, 0.f, 0.f, 0.f};
    f32x4 a3 = {0.f, 0.f, 0.f, 0.f};
    const u32x4 g = Gr;
    if (t + 2 < T_) {
        Pr = *(const f32x4*)(p0 + (size_t)(t + 2) * D_);
        Gr = *(const u32x4*)(g0 + (size_t)(t + 2) * D_);
    }
    a0 = __builtin_amdgcn_mfma_f32_16x16x32_bf16(aW[0], fhi[0], a0, 0, 0, 0);
    a1 = __builtin_amdgcn_mfma_f32_16x16x32_bf16(aW[1], fhi[1], a1, 0, 0, 0);
    a2 = __builtin_amdgcn_mfma_f32_16x16x32_bf16(aW[2], fhi[2], a2, 0, 0, 0);
    a3 = __builtin_amdgcn_mfma_f32_16x16x32_bf16(aW[3], fhi[3], a3, 0, 0, 0);
    a0 = __builtin_amdgcn_mfma_f32_16x16x32_bf16(aW[0], flo[0], a0, 0, 0, 0);
    a1 = __builtin_amdgcn_mfma_f32_16x16x32_bf16(aW[1], flo[1], a1, 0, 0, 0);
    a2 = __builtin_amdgcn_mfma_f32_16x16x32_bf16(aW[2], flo[2], a2, 0, 0, 0);
    a3 = __builtin_amdgcn_mfma_f32_16x16x32_bf16(aW[3], flo[3], a3, 0, 0, 0);
    const f32x4 acc = (a0 + a1) + (a2 + a3);

    f32x4 bn;
#pragma unroll
    for (int r = 0; r < 4; ++r) {
        const float th = tanh_f(acc[r]);
        bn[r] = h_lo(g[r]) * bold[r] + h_hi(g[r]) * th;
    }
    bold = bn;
    *(f32x4*)(o0 + (size_t)t * D_) = bn;

    // hi/lo bf16 split: hi = rne_bf16(v), lo = rne_bf16(v - hi). One packed
    // convert per pair + shl/and extraction + sub.
    const unsigned int h0 = cvt_pk_bf16(bn[0], bn[1]);
    const unsigned int h1 = cvt_pk_bf16(bn[2], bn[3]);
    const float f0 = bits_as_f(h0 << 16);
    const float f1 = bits_as_f(h0 & 0xFFFF0000u);
    const float f2 = bits_as_f(h1 << 16);
    const float f3 = bits_as_f(h1 & 0xFFFF0000u);
    const unsigned int l0 = cvt_pk_bf16(bn[0] - f0, bn[1] - f1);
    const unsigned int l1 = cvt_pk_bf16(bn[2] - f2, bn[3] - f3);
    *(uint2*)&bhi[lw0] = make_uint2(h0, h1);
    *(uint2*)&blo[lw0] = make_uint2(l0, l1);

    // LDS-only barrier: do NOT drain vmcnt (prefetches/stores stay in flight).
    asm volatile("s_waitcnt lgkmcnt(0)\n\ts_barrier" ::: "memory");

#pragma unroll
    for (int k = 0; k < 4; ++k) {
        fhi[k] = *(const bf16x8*)&bhi[lr + k * 32 + quad * 8];
        flo[k] = *(const bf16x8*)&blo[lr + k * 32 + quad * 8];
    }
}

#define CHAIN_KERNEL(NAME, RQ)                                               \
__global__ __launch_bounds__(512) void NAME(                                 \
    const float* RQ Wp, const unsigned int* RQ G,                            \
    const float* RQ P, float* RQ Out)                                        \
{                                                                            \
    __shared__ __align__(16) unsigned short bl_hi[2][16 * 136];              \
    __shared__ __align__(16) unsigned short bl_lo[2][16 * 136];              \
    const int tid  = threadIdx.x;                                            \
    const int wave = tid >> 6, lane = tid & 63;                              \
    const int l15  = lane & 15, quad = lane >> 4;                            \
    const int e0   = (wave << 4) + (quad << 2);                              \
    const int b    = (blockIdx.x << 4) + l15;                                \
    bf16x8 aW[4];                                                            \
    _Pragma("unroll")                                                        \
    for (int k = 0; k < 4; ++k)                                              \
        aW[k] = load_w_frag(Wp, (wave << 4) + l15, k * 32 + quad * 8);       \
    const size_t srow = (size_t)b * T_ * D_;                                 \
    const float*        p0 = P   + srow + e0;                                \
    const unsigned int* g0 = G   + srow + e0;                                \
    float*              o0 = Out + srow + e0;                                \
    f32x4 Pa = *(const f32x4*)(p0);                                          \
    u32x4 Ga = *(const u32x4*)(g0);                                          \
    f32x4 Pb = *(const f32x4*)(p0 + D_);                                     \
    u32x4 Gb = *(const u32x4*)(g0 + D_);                                     \
    bf16x8 fhi[4], flo[4];                                                   \
    _Pragma("unroll")                                                        \
    for (int k = 0; k < 4; ++k) { fhi[k] = (bf16x8)0; flo[k] = (bf16x8)0; }  \
    f32x4 bold = {0.f, 0.f, 0.f, 0.f};                                       \
    const int lw0 = l15 * 136 + e0;                                          \
    const int lr  = l15 * 136;                                               \
    for (int t = 0; t < T_; t += 2) {                                        \
        chain_step(aW, fhi, flo, Pa, Ga, bold, p0, g0, o0,                   \
                   &bl_hi[1][0], &bl_lo[1][0], t, lw0, lr, quad);            \
        chain_step(aW, fhi, flo, Pb, Gb, bold, p0, g0, o0,                   \
                   &bl_hi[0][0], &bl_lo[0][0], t + 1, lw0, lr, quad);        \
    }                                                                        \
}

CHAIN_KERNEL(chain_split, __restrict__)
CHAIN_KERNEL(chain_alias, )

extern "C" void kernel_launch(void* const* d_in, const int* in_sizes, int n_in,
                              void* d_out, int out_size, void* d_ws, size_t ws_size,
                              hipStream_t stream)
{
    const float* ev = (const float*)d_in[0];
    const float* We = (const float*)d_in[1];
    const float* be = (const float*)d_in[2];
    const float* Wp = (const float*)d_in[3];
    const float* bp = (const float*)d_in[4];
    const float* Wl = (const float*)d_in[5];
    const float* bl = (const float*)d_in[6];
    const float* Ww = (const float*)d_in[7];
    const float* bw = (const float*)d_in[8];
    float* out = (float*)d_out;
    (void)in_sizes; (void)n_in; (void)out_size;

    const size_t elems = (size_t)B_ * T_ * D_;
    if (ws_size >= elems * 8) {
        // Split layout: P in ws[0 .. elems*4), G in ws[elems*4 .. elems*8).
        float* Pbuf = (float*)d_ws;
        unsigned int* G = (unsigned int*)((char*)d_ws + elems * sizeof(float));
        proj_kernel<<<1024, 512, 0, stream>>>(ev, We, be, Wl, bl, Ww, bw, bp, Pbuf, G);
        chain_split<<<16, 512, 0, stream>>>(Wp, G, Pbuf, out);
    } else {
        // Fallback (== R2): P staged in Out, G in ws.
        unsigned int* G = (unsigned int*)d_ws;
        proj_kernel<<<1024, 512, 0, stream>>>(ev, We, be, Wl, bl, Ww, bw, bp, out, G);
        chain_alias<<<16, 512, 0, stream>>>(Wp, G, out, out);
    }
}